// Round 1
// baseline (990.832 us; speedup 1.0000x reference)
//
#include <hip/hip_runtime.h>

#define N_NODES 100000
#define C_IN    128
#define F       116
#define FF      (F * F)      // 13456
#define H1      256
#define NCL     64
#define EPS_BN   1e-5f
#define EPS_CORR 1e-12f

// ---------------- stage 0: bucket nodes by label ----------------

__global__ __launch_bounds__(256) void k_hist(const int* __restrict__ lab,
                                              int* __restrict__ cnt) {
    __shared__ int lh[C_IN];
    int t = threadIdx.x;
    if (t < C_IN) lh[t] = 0;
    __syncthreads();
    for (int n = blockIdx.x * blockDim.x + t; n < N_NODES; n += gridDim.x * blockDim.x)
        atomicAdd(&lh[lab[n]], 1);
    __syncthreads();
    if (t < C_IN) {
        int v = lh[t];
        if (v) atomicAdd(&cnt[t], v);
    }
}

__global__ __launch_bounds__(128) void k_prefix(const int* __restrict__ cnt,
                                                int* __restrict__ coff,
                                                int* __restrict__ cursor) {
    __shared__ int s[C_IN];
    int t = threadIdx.x;                // 0..127
    int mine = cnt[t];
    s[t] = mine;
    __syncthreads();
    for (int d = 1; d < C_IN; d <<= 1) {
        int v = (t >= d) ? s[t - d] : 0;
        __syncthreads();
        s[t] += v;
        __syncthreads();
    }
    int excl = s[t] - mine;             // exclusive prefix
    coff[t] = excl;
    cursor[t * 8] = excl;               // padded cursors (spread atomics)
    if (t == C_IN - 1) coff[C_IN] = s[t];
}

__global__ __launch_bounds__(256) void k_scatter(const int* __restrict__ lab,
                                                 int* __restrict__ cursor,
                                                 int* __restrict__ bucket) {
    int stride = gridDim.x * blockDim.x;
    for (int n = blockIdx.x * blockDim.x + threadIdx.x; n < N_NODES; n += stride) {
        int l = lab[n];
        int pos = atomicAdd(&cursor[l * 8], 1);
        bucket[pos] = n;
    }
}

// ---------------- stage 1: segment sum (the big one) ----------------
// grid = (14, 128): blockIdx.y = label, blockIdx.x = 1024-column chunk.
// Each thread owns 4 consecutive columns (float4), loops over the label's
// node list. No atomics; every x_cov byte read exactly once, coalesced.

__global__ __launch_bounds__(256) void k_segsum(const float* __restrict__ x,
                                                const int* __restrict__ bucket,
                                                const int* __restrict__ coff,
                                                float* __restrict__ cov) {
    const int label = blockIdx.y;
    const int col   = blockIdx.x * 256 + threadIdx.x;   // float4 index, row has 3364
    const bool valid = col < (FF / 4);
    const int j4 = (valid ? col : (FF / 4 - 1)) * 4;    // clamp; invalid lanes do harmless dup loads

    const int beg = coff[label];
    const int end = coff[label + 1];

    __shared__ int nd[256];
    float4 acc = make_float4(0.f, 0.f, 0.f, 0.f);

    for (int base = beg; base < end; base += 256) {
        int cl = end - base;
        if (cl > 256) cl = 256;
        __syncthreads();
        if (threadIdx.x < cl) nd[threadIdx.x] = bucket[base + threadIdx.x];
        __syncthreads();

        int i = 0;
        for (; i + 4 <= cl; i += 4) {
            int n0 = nd[i], n1 = nd[i + 1], n2 = nd[i + 2], n3 = nd[i + 3];
            float4 a0 = *(const float4*)(x + (size_t)n0 * FF + j4);
            float4 a1 = *(const float4*)(x + (size_t)n1 * FF + j4);
            float4 a2 = *(const float4*)(x + (size_t)n2 * FF + j4);
            float4 a3 = *(const float4*)(x + (size_t)n3 * FF + j4);
            acc.x += a0.x; acc.y += a0.y; acc.z += a0.z; acc.w += a0.w;
            acc.x += a1.x; acc.y += a1.y; acc.z += a1.z; acc.w += a1.w;
            acc.x += a2.x; acc.y += a2.y; acc.z += a2.z; acc.w += a2.w;
            acc.x += a3.x; acc.y += a3.y; acc.z += a3.z; acc.w += a3.w;
        }
        for (; i < cl; ++i) {
            float4 a = *(const float4*)(x + (size_t)nd[i] * FF + j4);
            acc.x += a.x; acc.y += a.y; acc.z += a.z; acc.w += a.w;
        }
    }

    if (valid)
        *(float4*)(cov + (size_t)label * FF + j4) = acc;
}

// ---------------- stage 2: correlation readout ----------------

__global__ __launch_bounds__(128) void k_corr(const float* __restrict__ cov,
                                              float* __restrict__ xcorr) {
    const int c = blockIdx.x;
    const float* Cm = cov + (size_t)c * FF;
    __shared__ float d[F];
    int t = threadIdx.x;
    if (t < F) {
        float dg = Cm[t * F + t];
        d[t] = sqrtf(fmaxf(dg, 0.f));
    }
    __syncthreads();
    if (t < F) {
        float di = d[t];
        float s = 0.f;
        for (int j = 0; j < F; ++j)
            s += Cm[t * F + j] / (di * d[j] + EPS_CORR);
        xcorr[c * F + t] = s / (float)F;
    }
}

// ---------------- stage 3: MLP + gumbel ----------------

__global__ __launch_bounds__(128) void k_stats1(const float* __restrict__ xcorr,
                                                float* __restrict__ mu,
                                                float* __restrict__ rs) {
    int f = threadIdx.x;
    if (f >= F) return;
    float s = 0.f;
    for (int c = 0; c < C_IN; ++c) s += xcorr[c * F + f];
    float m = s / (float)C_IN;
    float v = 0.f;
    for (int c = 0; c < C_IN; ++c) {
        float dd = xcorr[c * F + f] - m;
        v += dd * dd;
    }
    v /= (float)C_IN;
    mu[f] = m;
    rs[f] = rsqrtf(v + EPS_BN);
}

__global__ __launch_bounds__(256) void k_mm1(const float* __restrict__ xcorr,
                                             const float* __restrict__ mu1,
                                             const float* __restrict__ rs1,
                                             const float* __restrict__ g1,
                                             const float* __restrict__ be1,
                                             const float* __restrict__ w1,
                                             const float* __restrict__ b1,
                                             float* __restrict__ h) {
    const int c = blockIdx.x;
    __shared__ float xb[F];
    int t = threadIdx.x;   // 256
    if (t < F) xb[t] = g1[t] * (xcorr[c * F + t] - mu1[t]) * rs1[t] + be1[t];
    __syncthreads();
    float acc = b1[t];
    const float* wr = w1 + t * F;
    for (int f = 0; f < F; ++f) acc += xb[f] * wr[f];
    h[c * H1 + t] = fmaxf(acc, 0.f);
}

__global__ __launch_bounds__(256) void k_stats2(const float* __restrict__ h,
                                                float* __restrict__ mu,
                                                float* __restrict__ rs) {
    int o = threadIdx.x;   // 256
    float s = 0.f;
    for (int c = 0; c < C_IN; ++c) s += h[c * H1 + o];
    float m = s / (float)C_IN;
    float v = 0.f;
    for (int c = 0; c < C_IN; ++c) {
        float dd = h[c * H1 + o] - m;
        v += dd * dd;
    }
    v /= (float)C_IN;
    mu[o] = m;
    rs[o] = rsqrtf(v + EPS_BN);
}

__global__ __launch_bounds__(64) void k_mm2(const float* __restrict__ h,
                                            const float* __restrict__ mu2,
                                            const float* __restrict__ rs2,
                                            const float* __restrict__ g2,
                                            const float* __restrict__ be2,
                                            const float* __restrict__ w2,
                                            const float* __restrict__ b2,
                                            const float* __restrict__ gu,
                                            float* __restrict__ mask) {
    const int c = blockIdx.x;
    const int k = threadIdx.x;   // 64 = one wave
    __shared__ float hb[H1];
    for (int o = k; o < H1; o += 64)
        hb[o] = g2[o] * (h[c * H1 + o] - mu2[o]) * rs2[o] + be2[o];
    __syncthreads();

    float acc = b2[k];
    const float* wr = w2 + k * H1;
    for (int o = 0; o < H1; ++o) acc += hb[o] * wr[o];

    float u = gu[c * NCL + k];
    u = fminf(fmaxf(u, 1e-6f), 1.f - 1e-6f);
    float z = acc - logf(-logf(u));

    // softmax over the 64-lane wave
    float m = z;
    for (int d = 32; d; d >>= 1) m = fmaxf(m, __shfl_xor(m, d));
    float e = expf(z - m);
    float s = e;
    for (int d = 32; d; d >>= 1) s += __shfl_xor(s, d);
    float y = e / s;

    // argmax, first-index tie-break (matches jnp.argmax)
    float bv = z; int bi = k;
    for (int d = 32; d; d >>= 1) {
        float ov = __shfl_xor(bv, d);
        int   oi = __shfl_xor(bi, d);
        if (ov > bv || (ov == bv && oi < bi)) { bv = ov; bi = oi; }
    }
    float hard = (k == bi) ? 1.f : 0.f;
    mask[c * NCL + k] = (hard - y) + y;   // straight-through, as written in ref
}

// ---------------- launcher ----------------

extern "C" void kernel_launch(void* const* d_in, const int* in_sizes, int n_in,
                              void* d_out, int out_size, void* d_ws, size_t ws_size,
                              hipStream_t stream) {
    const float* x_cov = (const float*)d_in[0];
    const int*   lab   = (const int*)d_in[1];
    const float* gu    = (const float*)d_in[2];
    const float* w1    = (const float*)d_in[3];
    const float* b1    = (const float*)d_in[4];
    const float* g1    = (const float*)d_in[5];
    const float* be1   = (const float*)d_in[6];
    const float* w2    = (const float*)d_in[7];
    const float* b2    = (const float*)d_in[8];
    const float* g2    = (const float*)d_in[9];
    const float* be2   = (const float*)d_in[10];

    float* cov_out   = (float*)d_out;                    // [128, 116, 116]
    float* xcorr_out = cov_out + (size_t)C_IN * FF;      // [128, 116]
    float* mask_out  = xcorr_out + (size_t)C_IN * F;     // [128, 64]

    // workspace layout (ints then floats), 16B-aligned chunks
    int* bucket = (int*)d_ws;            // 100000
    int* cnt    = bucket + 100000;       // 128
    int* coff   = cnt + 128;             // 129 (pad to 132)
    int* cursor = coff + 132;            // 128 * 8 (padded)
    float* h    = (float*)(cursor + 1024);   // [128, 256]
    float* mu1  = h + C_IN * H1;
    float* rs1  = mu1 + 128;
    float* mu2  = rs1 + 128;
    float* rs2  = mu2 + 256;

    hipMemsetAsync(cnt, 0, C_IN * sizeof(int), stream);

    k_hist   <<<128, 256, 0, stream>>>(lab, cnt);
    k_prefix <<<1, 128, 0, stream>>>(cnt, coff, cursor);
    k_scatter<<<256, 256, 0, stream>>>(lab, cursor, bucket);

    k_segsum <<<dim3(14, C_IN), 256, 0, stream>>>(x_cov, bucket, coff, cov_out);

    k_corr   <<<C_IN, 128, 0, stream>>>(cov_out, xcorr_out);

    k_stats1 <<<1, 128, 0, stream>>>(xcorr_out, mu1, rs1);
    k_mm1    <<<C_IN, 256, 0, stream>>>(xcorr_out, mu1, rs1, g1, be1, w1, b1, h);
    k_stats2 <<<1, 256, 0, stream>>>(h, mu2, rs2);
    k_mm2    <<<C_IN, 64, 0, stream>>>(h, mu2, rs2, g2, be2, w2, b2, gu, mask_out);
}

// Round 2
// 966.466 us; speedup vs baseline: 1.0252x; 1.0252x over previous
//
#include <hip/hip_runtime.h>

#define N_NODES 100000
#define C_IN    128
#define F       116
#define FF      (F * F)      // 13456
#define H1      256
#define NCL     64
#define EPS_BN   1e-5f
#define EPS_CORR 1e-12f

#define NBLK 256             // bucketing blocks
#define NPB  ((N_NODES + NBLK - 1) / NBLK)   // 391 nodes per block

// ---------------- stage 0: stable counting sort by label ----------------

__global__ __launch_bounds__(256) void k_hist(const int* __restrict__ lab,
                                              int* __restrict__ blkhist) {
    __shared__ int lh[C_IN];
    const int b = blockIdx.x, t = threadIdx.x;
    if (t < C_IN) lh[t] = 0;
    __syncthreads();
    const int s = b * NPB;
    int e = s + NPB; if (e > N_NODES) e = N_NODES;
    for (int n = s + t; n < e; n += 256)
        atomicAdd(&lh[lab[n]], 1);
    __syncthreads();
    if (t < C_IN) blkhist[b * C_IN + t] = lh[t];
}

__global__ __launch_bounds__(128) void k_scan(const int* __restrict__ blkhist,
                                              int* __restrict__ blkoff,
                                              int* __restrict__ coff) {
    __shared__ int tot[C_IN];
    const int l = threadIdx.x;          // one label per thread
    int run = 0;
    for (int b = 0; b < NBLK; ++b) {
        int v = blkhist[b * C_IN + l];
        blkoff[b * C_IN + l] = run;
        run += v;
    }
    const int mine = run;
    tot[l] = run;
    __syncthreads();
    for (int d = 1; d < C_IN; d <<= 1) {   // inclusive scan over labels
        int v = (l >= d) ? tot[l - d] : 0;
        __syncthreads();
        tot[l] += v;
        __syncthreads();
    }
    coff[l] = tot[l] - mine;               // exclusive
    if (l == C_IN - 1) coff[C_IN] = tot[l];
}

__global__ __launch_bounds__(256) void k_scatter(const int* __restrict__ lab,
                                                 const int* __restrict__ blkoff,
                                                 const int* __restrict__ coff,
                                                 unsigned* __restrict__ bucket) {
    __shared__ int cur[C_IN];
    const int b = blockIdx.x, t = threadIdx.x;
    if (t < C_IN) cur[t] = coff[t] + blkoff[b * C_IN + t];
    __syncthreads();
    const int s = b * NPB;
    int e = s + NPB; if (e > N_NODES) e = N_NODES;
    for (int n = s + t; n < e; n += 256) {
        int l = lab[n];
        int pos = atomicAdd(&cur[l], 1);
        bucket[pos] = (unsigned)n * (unsigned)FF;   // pre-multiplied element offset
    }
}

// ---------------- stage 1: segment sum (the big one) ----------------
// grid = (14, 128): blockIdx.y = label, blockIdx.x = 1024-float-column chunk.
// Buckets are ~sorted ascending -> forward-walking 4KB gathers.

__global__ __launch_bounds__(256) void k_segsum(const float* __restrict__ x,
                                                const unsigned* __restrict__ bucket,
                                                const int* __restrict__ coff,
                                                float* __restrict__ cov) {
    const int label = blockIdx.y;
    const int col   = blockIdx.x * 256 + threadIdx.x;   // float4 index; row has 3364
    const bool valid = col < (FF / 4);
    const int j4 = (valid ? col : (FF / 4 - 1)) * 4;

    const int beg = coff[label];
    const int end = coff[label + 1];

    __shared__ unsigned nd[1024];
    float4 a0acc = make_float4(0.f, 0.f, 0.f, 0.f);
    float4 a1acc = make_float4(0.f, 0.f, 0.f, 0.f);

    for (int base = beg; base < end; base += 1024) {
        int cl = end - base;
        if (cl > 1024) cl = 1024;
        __syncthreads();
        for (int i = threadIdx.x; i < cl; i += 256)
            nd[i] = bucket[base + i];
        __syncthreads();

        int i = 0;
        for (; i + 4 <= cl; i += 4) {
            const float4 v0 = *(const float4*)(x + (size_t)nd[i]     + j4);
            const float4 v1 = *(const float4*)(x + (size_t)nd[i + 1] + j4);
            const float4 v2 = *(const float4*)(x + (size_t)nd[i + 2] + j4);
            const float4 v3 = *(const float4*)(x + (size_t)nd[i + 3] + j4);
            a0acc.x += v0.x; a0acc.y += v0.y; a0acc.z += v0.z; a0acc.w += v0.w;
            a1acc.x += v1.x; a1acc.y += v1.y; a1acc.z += v1.z; a1acc.w += v1.w;
            a0acc.x += v2.x; a0acc.y += v2.y; a0acc.z += v2.z; a0acc.w += v2.w;
            a1acc.x += v3.x; a1acc.y += v3.y; a1acc.z += v3.z; a1acc.w += v3.w;
        }
        for (; i < cl; ++i) {
            const float4 v = *(const float4*)(x + (size_t)nd[i] + j4);
            a0acc.x += v.x; a0acc.y += v.y; a0acc.z += v.z; a0acc.w += v.w;
        }
    }

    if (valid) {
        float4 r;
        r.x = a0acc.x + a1acc.x; r.y = a0acc.y + a1acc.y;
        r.z = a0acc.z + a1acc.z; r.w = a0acc.w + a1acc.w;
        *(float4*)(cov + (size_t)label * FF + j4) = r;
    }
}

// ---------------- stage 2: correlation readout ----------------

__global__ __launch_bounds__(128) void k_corr(const float* __restrict__ cov,
                                              float* __restrict__ xcorr) {
    const int c = blockIdx.x;
    const float* Cm = cov + (size_t)c * FF;
    __shared__ float d[F];
    const int t = threadIdx.x;
    if (t < F) d[t] = sqrtf(fmaxf(Cm[t * F + t], 0.f));
    __syncthreads();
    if (t < F) {
        const float di = d[t];
        float s = 0.f;
        for (int j = 0; j < F; ++j)
            s += Cm[t * F + j] / (di * d[j] + EPS_CORR);
        xcorr[c * F + t] = s / (float)F;
    }
}

// ---------------- stage 3: fused BN+MLP+gumbel ----------------

__global__ __launch_bounds__(256) void k_mm1(const float* __restrict__ xcorr,
                                             const float* __restrict__ g1,
                                             const float* __restrict__ be1,
                                             const float* __restrict__ w1,
                                             const float* __restrict__ b1,
                                             float* __restrict__ h) {
    const int c = blockIdx.x;
    const int t = threadIdx.x;
    __shared__ float xb[F];
    if (t < F) {
        // two-pass BN stats over the 128 clusters (L2-resident, 59 KB)
        float s = 0.f;
        for (int cc = 0; cc < C_IN; ++cc) s += xcorr[cc * F + t];
        const float m = s / (float)C_IN;
        float v = 0.f;
        for (int cc = 0; cc < C_IN; ++cc) {
            const float dd = xcorr[cc * F + t] - m;
            v += dd * dd;
        }
        v /= (float)C_IN;
        xb[t] = g1[t] * (xcorr[c * F + t] - m) * rsqrtf(v + EPS_BN) + be1[t];
    }
    __syncthreads();
    float acc = b1[t];
    const float* wr = w1 + t * F;
    for (int f = 0; f < F; ++f) acc += xb[f] * wr[f];
    h[c * H1 + t] = fmaxf(acc, 0.f);
}

__global__ __launch_bounds__(256) void k_mm2(const float* __restrict__ h,
                                             const float* __restrict__ g2,
                                             const float* __restrict__ be2,
                                             const float* __restrict__ w2,
                                             const float* __restrict__ b2,
                                             const float* __restrict__ gu,
                                             float* __restrict__ mask) {
    const int c = blockIdx.x;
    const int t = threadIdx.x;
    __shared__ float hb[H1];
    __shared__ float part[4][NCL];

    // BN stats for feature t over 128 clusters (L2-resident, 128 KB)
    {
        float s = 0.f;
        for (int cc = 0; cc < C_IN; ++cc) s += h[cc * H1 + t];
        const float m = s / (float)C_IN;
        float v = 0.f;
        for (int cc = 0; cc < C_IN; ++cc) {
            const float dd = h[cc * H1 + t] - m;
            v += dd * dd;
        }
        v /= (float)C_IN;
        hb[t] = g2[t] * (h[c * H1 + t] - m) * rsqrtf(v + EPS_BN) + be2[t];
    }
    __syncthreads();

    // split the 256-length dot over 4 thread groups
    const int k = t & 63, p = t >> 6;
    float acc = 0.f;
    const float* wr = w2 + k * H1 + p * 64;
    const float* hp = hb + p * 64;
    for (int o = 0; o < 64; ++o) acc += hp[o] * wr[o];
    part[p][k] = acc;
    __syncthreads();

    if (t < NCL) {  // wave 0
        float z = b2[t] + part[0][t] + part[1][t] + part[2][t] + part[3][t];
        float u = gu[c * NCL + t];
        u = fminf(fmaxf(u, 1e-6f), 1.f - 1e-6f);
        z = z - logf(-logf(u));

        float m = z;
        for (int d = 32; d; d >>= 1) m = fmaxf(m, __shfl_xor(m, d));
        const float e = expf(z - m);
        float s = e;
        for (int d = 32; d; d >>= 1) s += __shfl_xor(s, d);
        const float y = e / s;

        float bv = z; int bi = t;
        for (int d = 32; d; d >>= 1) {
            float ov = __shfl_xor(bv, d);
            int   oi = __shfl_xor(bi, d);
            if (ov > bv || (ov == bv && oi < bi)) { bv = ov; bi = oi; }
        }
        const float hard = (t == bi) ? 1.f : 0.f;
        mask[c * NCL + t] = (hard - y) + y;
    }
}

// ---------------- launcher ----------------

extern "C" void kernel_launch(void* const* d_in, const int* in_sizes, int n_in,
                              void* d_out, int out_size, void* d_ws, size_t ws_size,
                              hipStream_t stream) {
    const float* x_cov = (const float*)d_in[0];
    const int*   lab   = (const int*)d_in[1];
    const float* gu    = (const float*)d_in[2];
    const float* w1    = (const float*)d_in[3];
    const float* b1    = (const float*)d_in[4];
    const float* g1    = (const float*)d_in[5];
    const float* be1   = (const float*)d_in[6];
    const float* w2    = (const float*)d_in[7];
    const float* b2    = (const float*)d_in[8];
    const float* g2    = (const float*)d_in[9];
    const float* be2   = (const float*)d_in[10];

    float* cov_out   = (float*)d_out;                    // [128, 116, 116]
    float* xcorr_out = cov_out + (size_t)C_IN * FF;      // [128, 116]
    float* mask_out  = xcorr_out + (size_t)C_IN * F;     // [128, 64]

    // workspace layout
    int*      blkhist = (int*)d_ws;                      // 256*128
    int*      blkoff  = blkhist + NBLK * C_IN;           // 256*128
    int*      coff    = blkoff + NBLK * C_IN;            // 129 (pad 132)
    unsigned* bucket  = (unsigned*)(coff + 132);         // 100000
    float*    h       = (float*)(bucket + N_NODES);      // 128*256

    k_hist   <<<NBLK, 256, 0, stream>>>(lab, blkhist);
    k_scan   <<<1, 128, 0, stream>>>(blkhist, blkoff, coff);
    k_scatter<<<NBLK, 256, 0, stream>>>(lab, blkoff, coff, bucket);

    k_segsum <<<dim3(14, C_IN), 256, 0, stream>>>(x_cov, bucket, coff, cov_out);

    k_corr   <<<C_IN, 128, 0, stream>>>(cov_out, xcorr_out);
    k_mm1    <<<C_IN, 256, 0, stream>>>(xcorr_out, g1, be1, w1, b1, h);
    k_mm2    <<<C_IN, 256, 0, stream>>>(h, g2, be2, w2, b2, gu, mask_out);
}

// Round 3
// 891.735 us; speedup vs baseline: 1.1111x; 1.0838x over previous
//
#include <hip/hip_runtime.h>

#define N_NODES 100000
#define C_IN    128
#define F       116
#define FF      (F * F)      // 13456
#define H1      256
#define NCL     64
#define EPS_BN   1e-5f
#define EPS_CORR 1e-12f

#define NBLK 128             // bucketing blocks
#define NPB  ((N_NODES + NBLK - 1) / NBLK)   // 782 nodes per block

typedef float f32x4 __attribute__((ext_vector_type(4)));

// ---------------- stage 0: stable counting sort by label ----------------

__global__ __launch_bounds__(256) void k_hist(const int* __restrict__ lab,
                                              int* __restrict__ blkhist) {
    __shared__ int lh[C_IN];
    const int b = blockIdx.x, t = threadIdx.x;
    if (t < C_IN) lh[t] = 0;
    __syncthreads();
    const int s = b * NPB;
    int e = s + NPB; if (e > N_NODES) e = N_NODES;
    for (int n = s + t; n < e; n += 256)
        atomicAdd(&lh[lab[n]], 1);
    __syncthreads();
    if (t < C_IN) blkhist[b * C_IN + t] = lh[t];
}

__global__ __launch_bounds__(128) void k_scan(const int* __restrict__ blkhist,
                                              int* __restrict__ blkoff,
                                              int* __restrict__ coff) {
    __shared__ int hl[NBLK * C_IN];     // 64 KB
    __shared__ int tot[C_IN];
    const int l = threadIdx.x;          // 128 threads
    for (int i = l; i < NBLK * C_IN; i += 128) hl[i] = blkhist[i];
    __syncthreads();
    int run = 0;
    for (int b = 0; b < NBLK; ++b) {    // hl[b*C_IN + l]: stride-1 across lanes
        int v = hl[b * C_IN + l];
        hl[b * C_IN + l] = run;
        run += v;
    }
    const int mine = run;
    tot[l] = run;
    __syncthreads();
    for (int d = 1; d < C_IN; d <<= 1) {
        int v = (l >= d) ? tot[l - d] : 0;
        __syncthreads();
        tot[l] += v;
        __syncthreads();
    }
    coff[l] = tot[l] - mine;
    if (l == C_IN - 1) coff[C_IN] = tot[l];
    __syncthreads();
    for (int i = l; i < NBLK * C_IN; i += 128) blkoff[i] = hl[i];
}

__global__ __launch_bounds__(256) void k_scatter(const int* __restrict__ lab,
                                                 const int* __restrict__ blkoff,
                                                 const int* __restrict__ coff,
                                                 unsigned* __restrict__ bucket) {
    __shared__ int cur[C_IN];
    const int b = blockIdx.x, t = threadIdx.x;
    if (t < C_IN) cur[t] = coff[t] + blkoff[b * C_IN + t];
    __syncthreads();
    const int s = b * NPB;
    int e = s + NPB; if (e > N_NODES) e = N_NODES;
    for (int n = s + t; n < e; n += 256) {
        int l = lab[n];
        int pos = atomicAdd(&cur[l], 1);
        bucket[pos] = (unsigned)n * (unsigned)FF;   // pre-multiplied element offset
    }
}

// ---------------- stage 1: segment sum (the big one) ----------------
// grid = (14, 128): blockIdx.y = label, blockIdx.x = 1024-float-column chunk.
// Buckets are block-sorted ascending -> mostly-forward 4KB gathers.

__global__ __launch_bounds__(256) void k_segsum(const float* __restrict__ x,
                                                const unsigned* __restrict__ bucket,
                                                const int* __restrict__ coff,
                                                float* __restrict__ cov) {
    const int label = blockIdx.y;
    const int col   = blockIdx.x * 256 + threadIdx.x;   // float4 index; row has 3364
    const bool valid = col < (FF / 4);
    const int j4 = (valid ? col : (FF / 4 - 1)) * 4;

    const int beg = coff[label];
    const int end = coff[label + 1];

    __shared__ unsigned nd[1024];
    f32x4 acc0 = (f32x4)(0.f);
    f32x4 acc1 = (f32x4)(0.f);

    for (int base = beg; base < end; base += 1024) {
        int cl = end - base;
        if (cl > 1024) cl = 1024;
        __syncthreads();
        for (int i = threadIdx.x; i < cl; i += 256)
            nd[i] = bucket[base + i];
        __syncthreads();

        int i = 0;
        for (; i + 4 <= cl; i += 4) {
            const f32x4 v0 = __builtin_nontemporal_load((const f32x4*)(x + (size_t)nd[i]     + j4));
            const f32x4 v1 = __builtin_nontemporal_load((const f32x4*)(x + (size_t)nd[i + 1] + j4));
            const f32x4 v2 = __builtin_nontemporal_load((const f32x4*)(x + (size_t)nd[i + 2] + j4));
            const f32x4 v3 = __builtin_nontemporal_load((const f32x4*)(x + (size_t)nd[i + 3] + j4));
            acc0 += v0; acc1 += v1; acc0 += v2; acc1 += v3;
        }
        for (; i < cl; ++i) {
            const f32x4 v = __builtin_nontemporal_load((const f32x4*)(x + (size_t)nd[i] + j4));
            acc0 += v;
        }
    }

    if (valid) {
        const f32x4 r = acc0 + acc1;
        *(f32x4*)(cov + (size_t)label * FF + j4) = r;
    }
}

// ---------------- stage 2: correlation readout ----------------

__global__ __launch_bounds__(128) void k_corr(const float* __restrict__ cov,
                                              float* __restrict__ xcorr) {
    const int c = blockIdx.x;
    const float* Cm = cov + (size_t)c * FF;
    __shared__ float d[F];
    const int t = threadIdx.x;
    if (t < F) d[t] = sqrtf(fmaxf(Cm[t * F + t], 0.f));
    __syncthreads();
    if (t < F) {
        const float di = d[t];
        float s = 0.f;
        for (int j = 0; j < F; ++j)
            s += Cm[t * F + j] * __builtin_amdgcn_rcpf(di * d[j] + EPS_CORR);
        xcorr[c * F + t] = s * (1.f / (float)F);
    }
}

// ---------------- stage 3: fused BN+MLP+gumbel ----------------

__global__ __launch_bounds__(256) void k_mm1(const float* __restrict__ xcorr,
                                             const float* __restrict__ g1,
                                             const float* __restrict__ be1,
                                             const float* __restrict__ w1,
                                             const float* __restrict__ b1,
                                             float* __restrict__ h) {
    const int c = blockIdx.x;
    const int t = threadIdx.x;
    __shared__ float xb[F];
    if (t < F) {
        float s = 0.f;
        for (int cc = 0; cc < C_IN; ++cc) s += xcorr[cc * F + t];
        const float m = s / (float)C_IN;
        float v = 0.f;
        for (int cc = 0; cc < C_IN; ++cc) {
            const float dd = xcorr[cc * F + t] - m;
            v += dd * dd;
        }
        v /= (float)C_IN;
        xb[t] = g1[t] * (xcorr[c * F + t] - m) * rsqrtf(v + EPS_BN) + be1[t];
    }
    __syncthreads();
    float acc = b1[t];
    const float* wr = w1 + t * F;
    for (int f = 0; f < F; ++f) acc += xb[f] * wr[f];
    h[c * H1 + t] = fmaxf(acc, 0.f);
}

__global__ __launch_bounds__(256) void k_mm2(const float* __restrict__ h,
                                             const float* __restrict__ g2,
                                             const float* __restrict__ be2,
                                             const float* __restrict__ w2,
                                             const float* __restrict__ b2,
                                             const float* __restrict__ gu,
                                             float* __restrict__ mask) {
    const int c = blockIdx.x;
    const int t = threadIdx.x;
    __shared__ float hb[H1];
    __shared__ float part[4][NCL];

    {
        float s = 0.f;
        for (int cc = 0; cc < C_IN; ++cc) s += h[cc * H1 + t];
        const float m = s / (float)C_IN;
        float v = 0.f;
        for (int cc = 0; cc < C_IN; ++cc) {
            const float dd = h[cc * H1 + t] - m;
            v += dd * dd;
        }
        v /= (float)C_IN;
        hb[t] = g2[t] * (h[c * H1 + t] - m) * rsqrtf(v + EPS_BN) + be2[t];
    }
    __syncthreads();

    const int k = t & 63, p = t >> 6;
    float acc = 0.f;
    const float* wr = w2 + k * H1 + p * 64;
    const float* hp = hb + p * 64;
    for (int o = 0; o < 64; ++o) acc += hp[o] * wr[o];
    part[p][k] = acc;
    __syncthreads();

    if (t < NCL) {  // wave 0
        float z = b2[t] + part[0][t] + part[1][t] + part[2][t] + part[3][t];
        float u = gu[c * NCL + t];
        u = fminf(fmaxf(u, 1e-6f), 1.f - 1e-6f);
        z = z - logf(-logf(u));

        float m = z;
        for (int d = 32; d; d >>= 1) m = fmaxf(m, __shfl_xor(m, d));
        const float e = expf(z - m);
        float s = e;
        for (int d = 32; d; d >>= 1) s += __shfl_xor(s, d);
        const float y = e / s;

        float bv = z; int bi = t;
        for (int d = 32; d; d >>= 1) {
            float ov = __shfl_xor(bv, d);
            int   oi = __shfl_xor(bi, d);
            if (ov > bv || (ov == bv && oi < bi)) { bv = ov; bi = oi; }
        }
        const float hard = (t == bi) ? 1.f : 0.f;
        mask[c * NCL + t] = (hard - y) + y;
    }
}

// ---------------- launcher ----------------

extern "C" void kernel_launch(void* const* d_in, const int* in_sizes, int n_in,
                              void* d_out, int out_size, void* d_ws, size_t ws_size,
                              hipStream_t stream) {
    const float* x_cov = (const float*)d_in[0];
    const int*   lab   = (const int*)d_in[1];
    const float* gu    = (const float*)d_in[2];
    const float* w1    = (const float*)d_in[3];
    const float* b1    = (const float*)d_in[4];
    const float* g1    = (const float*)d_in[5];
    const float* be1   = (const float*)d_in[6];
    const float* w2    = (const float*)d_in[7];
    const float* b2    = (const float*)d_in[8];
    const float* g2    = (const float*)d_in[9];
    const float* be2   = (const float*)d_in[10];

    float* cov_out   = (float*)d_out;                    // [128, 116, 116]
    float* xcorr_out = cov_out + (size_t)C_IN * FF;      // [128, 116]
    float* mask_out  = xcorr_out + (size_t)C_IN * F;     // [128, 64]

    // workspace layout
    int*      blkhist = (int*)d_ws;                      // 128*128
    int*      blkoff  = blkhist + NBLK * C_IN;           // 128*128
    int*      coff    = blkoff + NBLK * C_IN;            // 129 (pad 132)
    unsigned* bucket  = (unsigned*)(coff + 132);         // 100000
    float*    h       = (float*)(bucket + N_NODES);      // 128*256

    k_hist   <<<NBLK, 256, 0, stream>>>(lab, blkhist);
    k_scan   <<<1, 128, 0, stream>>>(blkhist, blkoff, coff);
    k_scatter<<<NBLK, 256, 0, stream>>>(lab, blkoff, coff, bucket);

    k_segsum <<<dim3(14, C_IN), 256, 0, stream>>>(x_cov, bucket, coff, cov_out);

    k_corr   <<<C_IN, 128, 0, stream>>>(cov_out, xcorr_out);
    k_mm1    <<<C_IN, 256, 0, stream>>>(xcorr_out, g1, be1, w1, b1, h);
    k_mm2    <<<C_IN, 256, 0, stream>>>(h, g2, be2, w2, b2, gu, mask_out);
}